// Round 3
// baseline (909.759 us; speedup 1.0000x reference)
//
#include <hip/hip_runtime.h>
#include <math.h>

#define B_ 128
#define T_ 1024
#define H_ 256
#define Z_ 64
#define M_ (B_ * T_)   // 131072 rows

// ---------------------------------------------------------------------------
// Kernel 1: precompute the non-recurrent part of both matmuls.
//   pre_mu[m, n]  = sum_k H[m,k] * W_mu[n,k]  + b_mu[n]    (k over 0..255)
//   pre_std[m, n] = sum_k H[m,k] * W_std[n,k] + b_std[n]
// Tiled f32 GEMM: block = 256 threads (16x16), tile 64(M) x 64(N), K-step 16.
// ---------------------------------------------------------------------------
__global__ __launch_bounds__(256) void precompute_kernel(
    const float* __restrict__ Hm,    // [M_, 256]
    const float* __restrict__ Wmu,   // [64, 320]
    const float* __restrict__ Wstd,  // [64, 320]
    const float* __restrict__ bmu,   // [64]
    const float* __restrict__ bstd,  // [64]
    float* __restrict__ pre_mu,      // [M_, 64]
    float* __restrict__ pre_std)     // [M_, 64]
{
    const int tid = threadIdx.x;
    const int ty = tid >> 4;          // 0..15 -> 4 M-rows each
    const int tx = tid & 15;          // 0..15 -> 4 N-cols each
    const int m0 = blockIdx.x * 64;

    __shared__ float Ash[64][17];     // +1 pad: kills power-of-2 bank conflicts
    __shared__ float Wm[64][17];
    __shared__ float Ws[64][17];

    float accm[4][4] = {};
    float accs[4][4] = {};

    const int lrow = tid >> 2;        // 0..63
    const int lk   = (tid & 3) * 4;   // 0,4,8,12

    for (int k0 = 0; k0 < 256; k0 += 16) {
        float4 av  = *reinterpret_cast<const float4*>(&Hm[(size_t)(m0 + lrow) * H_ + k0 + lk]);
        float4 wmv = *reinterpret_cast<const float4*>(&Wmu[(size_t)lrow * 320 + k0 + lk]);
        float4 wsv = *reinterpret_cast<const float4*>(&Wstd[(size_t)lrow * 320 + k0 + lk]);
        __syncthreads();   // all threads done reading previous tiles
        Ash[lrow][lk + 0] = av.x;  Ash[lrow][lk + 1] = av.y;
        Ash[lrow][lk + 2] = av.z;  Ash[lrow][lk + 3] = av.w;
        Wm[lrow][lk + 0] = wmv.x;  Wm[lrow][lk + 1] = wmv.y;
        Wm[lrow][lk + 2] = wmv.z;  Wm[lrow][lk + 3] = wmv.w;
        Ws[lrow][lk + 0] = wsv.x;  Ws[lrow][lk + 1] = wsv.y;
        Ws[lrow][lk + 2] = wsv.z;  Ws[lrow][lk + 3] = wsv.w;
        __syncthreads();

        #pragma unroll
        for (int kk = 0; kk < 16; ++kk) {
            float a4[4], wm4[4], ws4[4];
            #pragma unroll
            for (int i = 0; i < 4; ++i) a4[i] = Ash[ty * 4 + i][kk];
            #pragma unroll
            for (int jj = 0; jj < 4; ++jj) wm4[jj] = Wm[tx * 4 + jj][kk];
            #pragma unroll
            for (int jj = 0; jj < 4; ++jj) ws4[jj] = Ws[tx * 4 + jj][kk];
            #pragma unroll
            for (int i = 0; i < 4; ++i)
                #pragma unroll
                for (int jj = 0; jj < 4; ++jj) {
                    accm[i][jj] += a4[i] * wm4[jj];
                    accs[i][jj] += a4[i] * ws4[jj];
                }
        }
    }

    float4 bm = *reinterpret_cast<const float4*>(&bmu[tx * 4]);
    float4 bs = *reinterpret_cast<const float4*>(&bstd[tx * 4]);
    #pragma unroll
    for (int i = 0; i < 4; ++i) {
        const size_t m = (size_t)(m0 + ty * 4 + i);
        float4 om, os;
        om.x = accm[i][0] + bm.x;  om.y = accm[i][1] + bm.y;
        om.z = accm[i][2] + bm.z;  om.w = accm[i][3] + bm.w;
        os.x = accs[i][0] + bs.x;  os.y = accs[i][1] + bs.y;
        os.z = accs[i][2] + bs.z;  os.w = accs[i][3] + bs.w;
        *reinterpret_cast<float4*>(&pre_mu[m * Z_ + tx * 4])  = om;
        *reinterpret_cast<float4*>(&pre_std[m * Z_ + tx * 4]) = os;
    }
}

// ---------------------------------------------------------------------------
// Kernel 2: the recurrence. One wave per batch row; lane j owns output
// element j. z_{t-1} never leaves registers: each step broadcasts the 64
// lane-private z values with v_readlane_b32 -> SGPR, feeding v_fmac_f32
// directly. NO LDS, NO barrier (removes the barrier-drain; R1 lesson).
//
// R2 lesson: VGPR_Count was 84 < the 128 VGPRs the weight rows need -> the
// allocator reloaded weights inside the loop, putting memory latency on the
// serial critical path (1760 cyc/step vs ~450 of real work).
// __launch_bounds__(64, 1) lifts the register budget to ~512 VGPRs/lane so
// amu/astd stay resident. We run 1 wave per CU anyway (128 blocks, 256 CUs),
// so minimum occupancy costs nothing.
// ---------------------------------------------------------------------------
__global__ __launch_bounds__(64, 1) void recurrent_kernel(
    const float* __restrict__ pre_mu,   // [M_, 64]
    const float* __restrict__ pre_std,  // [M_, 64]
    const float* __restrict__ eps,      // [B_, T_, 64]
    const float* __restrict__ Wmu,      // [64, 320]
    const float* __restrict__ Wstd,     // [64, 320]
    float* __restrict__ out)            // z | mu | std, each [B_, T_, 64]
{
    const int b = blockIdx.x;
    const int j = threadIdx.x;

    // recurrent weight rows in registers; float4 loads, static indexing after
    // full unroll so every element is register-resident.
    float amu[64], astd[64];
    {
        const float4* wm4 = reinterpret_cast<const float4*>(&Wmu[(size_t)j * 320 + 256]);
        const float4* ws4 = reinterpret_cast<const float4*>(&Wstd[(size_t)j * 320 + 256]);
        #pragma unroll
        for (int k = 0; k < 16; ++k) {
            const float4 a = wm4[k];
            const float4 s = ws4[k];
            amu[4 * k + 0] = a.x;  amu[4 * k + 1] = a.y;
            amu[4 * k + 2] = a.z;  amu[4 * k + 3] = a.w;
            astd[4 * k + 0] = s.x; astd[4 * k + 1] = s.y;
            astd[4 * k + 2] = s.z; astd[4 * k + 3] = s.w;
        }
    }

    const size_t base = (size_t)b * T_ * Z_;
    float* __restrict__ zo   = out;
    float* __restrict__ muo  = out + (size_t)M_ * Z_;
    float* __restrict__ stdo = out + (size_t)2 * M_ * Z_;

    // prefetch t = 0
    float pm = pre_mu[base + j];
    float ps = pre_std[base + j];
    float ev = eps[base + j];

    float z = 0.0f;   // z_{t-1}, lane j holds element j

    for (int t = 0; t < T_; ++t) {
        // prefetch t+1 (overlaps with this step's matvec; no barrier drain)
        float pm_n = 0.f, ps_n = 0.f, ev_n = 0.f;
        if (t + 1 < T_) {
            const size_t idx = base + (size_t)(t + 1) * Z_ + j;
            pm_n = pre_mu[idx];
            ps_n = pre_std[idx];
            ev_n = eps[idx];
        }

        // wave-broadcast matvec: 4 accumulators per output to break dep chains
        const unsigned zb = __float_as_uint(z);
        float am0 = pm, am1 = 0.f, am2 = 0.f, am3 = 0.f;
        float as0 = ps, as1 = 0.f, as2 = 0.f, as3 = 0.f;
        #pragma unroll
        for (int k = 0; k < 16; ++k) {
            const float z0 = __uint_as_float(__builtin_amdgcn_readlane(zb, 4 * k + 0));
            const float z1 = __uint_as_float(__builtin_amdgcn_readlane(zb, 4 * k + 1));
            const float z2 = __uint_as_float(__builtin_amdgcn_readlane(zb, 4 * k + 2));
            const float z3 = __uint_as_float(__builtin_amdgcn_readlane(zb, 4 * k + 3));
            am0 += z0 * amu[4 * k + 0];  as0 += z0 * astd[4 * k + 0];
            am1 += z1 * amu[4 * k + 1];  as1 += z1 * astd[4 * k + 1];
            am2 += z2 * amu[4 * k + 2];  as2 += z2 * astd[4 * k + 2];
            am3 += z3 * amu[4 * k + 3];  as3 += z3 * astd[4 * k + 3];
        }
        const float mu = (am0 + am1) + (am2 + am3);
        const float sx = (as0 + as1) + (as2 + as3);
        // softplus via hw transcendentals (abs err < 1e-7 in guarded range)
        const float sp = (sx > 20.0f) ? sx : __logf(1.0f + __expf(sx));
        const float sd = sp + 1e-4f;
        z = mu + ev * sd;

        const size_t o = base + (size_t)t * Z_ + j;
        zo[o]   = z;
        muo[o]  = mu;
        stdo[o] = sd;

        pm = pm_n; ps = ps_n; ev = ev_n;
    }
}

extern "C" void kernel_launch(void* const* d_in, const int* in_sizes, int n_in,
                              void* d_out, int out_size, void* d_ws, size_t ws_size,
                              hipStream_t stream) {
    const float* input_q = (const float*)d_in[0];  // [B, T, H]
    const float* eps     = (const float*)d_in[1];  // [B, T, Z]
    const float* W_mu    = (const float*)d_in[2];  // [Z, H+Z]
    const float* b_mu    = (const float*)d_in[3];  // [Z]
    const float* W_std   = (const float*)d_in[4];  // [Z, H+Z]
    const float* b_std   = (const float*)d_in[5];  // [Z]
    float* out = (float*)d_out;

    float* pre_mu  = (float*)d_ws;                      // [M_, 64]
    float* pre_std = pre_mu + (size_t)M_ * Z_;          // [M_, 64]

    precompute_kernel<<<M_ / 64, 256, 0, stream>>>(
        input_q, W_mu, W_std, b_mu, b_std, pre_mu, pre_std);

    recurrent_kernel<<<B_, 64, 0, stream>>>(
        pre_mu, pre_std, eps, W_mu, W_std, out);
}

// Round 4
// 648.638 us; speedup vs baseline: 1.4026x; 1.4026x over previous
//
#include <hip/hip_runtime.h>
#include <math.h>

#define B_ 128
#define T_ 1024
#define H_ 256
#define Z_ 64
#define M_ (B_ * T_)   // 131072 rows

// ---------------------------------------------------------------------------
// Kernel 1: precompute the non-recurrent part of both matmuls.
//   pre_mu[m, n]  = sum_k H[m,k] * W_mu[n,k]  + b_mu[n]    (k over 0..255)
//   pre_std[m, n] = sum_k H[m,k] * W_std[n,k] + b_std[n]
// Tiled f32 GEMM: block = 256 threads (16x16), tile 64(M) x 64(N), K-step 16.
// ---------------------------------------------------------------------------
__global__ __launch_bounds__(256) void precompute_kernel(
    const float* __restrict__ Hm,    // [M_, 256]
    const float* __restrict__ Wmu,   // [64, 320]
    const float* __restrict__ Wstd,  // [64, 320]
    const float* __restrict__ bmu,   // [64]
    const float* __restrict__ bstd,  // [64]
    float* __restrict__ pre_mu,      // [M_, 64]
    float* __restrict__ pre_std)     // [M_, 64]
{
    const int tid = threadIdx.x;
    const int ty = tid >> 4;          // 0..15 -> 4 M-rows each
    const int tx = tid & 15;          // 0..15 -> 4 N-cols each
    const int m0 = blockIdx.x * 64;

    __shared__ float Ash[64][17];     // +1 pad: kills power-of-2 bank conflicts
    __shared__ float Wm[64][17];
    __shared__ float Ws[64][17];

    float accm[4][4] = {};
    float accs[4][4] = {};

    const int lrow = tid >> 2;        // 0..63
    const int lk   = (tid & 3) * 4;   // 0,4,8,12

    for (int k0 = 0; k0 < 256; k0 += 16) {
        float4 av  = *reinterpret_cast<const float4*>(&Hm[(size_t)(m0 + lrow) * H_ + k0 + lk]);
        float4 wmv = *reinterpret_cast<const float4*>(&Wmu[(size_t)lrow * 320 + k0 + lk]);
        float4 wsv = *reinterpret_cast<const float4*>(&Wstd[(size_t)lrow * 320 + k0 + lk]);
        __syncthreads();   // all threads done reading previous tiles
        Ash[lrow][lk + 0] = av.x;  Ash[lrow][lk + 1] = av.y;
        Ash[lrow][lk + 2] = av.z;  Ash[lrow][lk + 3] = av.w;
        Wm[lrow][lk + 0] = wmv.x;  Wm[lrow][lk + 1] = wmv.y;
        Wm[lrow][lk + 2] = wmv.z;  Wm[lrow][lk + 3] = wmv.w;
        Ws[lrow][lk + 0] = wsv.x;  Ws[lrow][lk + 1] = wsv.y;
        Ws[lrow][lk + 2] = wsv.z;  Ws[lrow][lk + 3] = wsv.w;
        __syncthreads();

        #pragma unroll
        for (int kk = 0; kk < 16; ++kk) {
            float a4[4], wm4[4], ws4[4];
            #pragma unroll
            for (int i = 0; i < 4; ++i) a4[i] = Ash[ty * 4 + i][kk];
            #pragma unroll
            for (int jj = 0; jj < 4; ++jj) wm4[jj] = Wm[tx * 4 + jj][kk];
            #pragma unroll
            for (int jj = 0; jj < 4; ++jj) ws4[jj] = Ws[tx * 4 + jj][kk];
            #pragma unroll
            for (int i = 0; i < 4; ++i)
                #pragma unroll
                for (int jj = 0; jj < 4; ++jj) {
                    accm[i][jj] += a4[i] * wm4[jj];
                    accs[i][jj] += a4[i] * ws4[jj];
                }
        }
    }

    float4 bm = *reinterpret_cast<const float4*>(&bmu[tx * 4]);
    float4 bs = *reinterpret_cast<const float4*>(&bstd[tx * 4]);
    #pragma unroll
    for (int i = 0; i < 4; ++i) {
        const size_t m = (size_t)(m0 + ty * 4 + i);
        float4 om, os;
        om.x = accm[i][0] + bm.x;  om.y = accm[i][1] + bm.y;
        om.z = accm[i][2] + bm.z;  om.w = accm[i][3] + bm.w;
        os.x = accs[i][0] + bs.x;  os.y = accs[i][1] + bs.y;
        os.z = accs[i][2] + bs.z;  os.w = accs[i][3] + bs.w;
        *reinterpret_cast<float4*>(&pre_mu[m * Z_ + tx * 4])  = om;
        *reinterpret_cast<float4*>(&pre_std[m * Z_ + tx * 4]) = os;
    }
}

// ---------------------------------------------------------------------------
// Kernel 2: the recurrence. One wave per batch row; lane j owns output
// element j. z_{t-1} never leaves registers: wave-broadcast via
// v_readlane_b32 -> SGPR feeding v_fmac_f32. NO LDS, NO barrier (R1 lesson:
// the __syncthreads barrier-drain put store latency on the critical path).
//
// R3 lesson: __launch_bounds__(64,1) only RAISES the VGPR cap; the scheduler
// still TARGETS high occupancy and rematerializes the (invariant) weight
// loads inside the loop instead of keeping 128 VGPRs live -> VGPR_Count
// stayed 84 and every step paid ~128 latency-exposed reloads (1800 cy/step).
// Fix: amdgpu_waves_per_eu(1,1) forces the occupancy TARGET to 1 (budget =
// full 512 VGPRs), and an empty asm "+v" pin on every weight makes the
// values asm-defined -> non-rematerializable. We run 1 wave/CU anyway
// (128 blocks, 256 CUs), so max-1-wave/EU costs nothing.
// ---------------------------------------------------------------------------
__global__ __launch_bounds__(64)
__attribute__((amdgpu_waves_per_eu(1, 1)))
void recurrent_kernel(
    const float* __restrict__ pre_mu,   // [M_, 64]
    const float* __restrict__ pre_std,  // [M_, 64]
    const float* __restrict__ eps,      // [B_, T_, 64]
    const float* __restrict__ Wmu,      // [64, 320]
    const float* __restrict__ Wstd,     // [64, 320]
    float* __restrict__ out)            // z | mu | std, each [B_, T_, 64]
{
    const int b = blockIdx.x;
    const int j = threadIdx.x;

    // recurrent weight rows in registers; float4 loads, static indexing after
    // full unroll, then pin each value so the allocator can't remat the load.
    float amu[64], astd[64];
    {
        const float4* wm4 = reinterpret_cast<const float4*>(&Wmu[(size_t)j * 320 + 256]);
        const float4* ws4 = reinterpret_cast<const float4*>(&Wstd[(size_t)j * 320 + 256]);
        #pragma unroll
        for (int k = 0; k < 16; ++k) {
            const float4 a = wm4[k];
            const float4 s = ws4[k];
            amu[4 * k + 0] = a.x;  amu[4 * k + 1] = a.y;
            amu[4 * k + 2] = a.z;  amu[4 * k + 3] = a.w;
            astd[4 * k + 0] = s.x; astd[4 * k + 1] = s.y;
            astd[4 * k + 2] = s.z; astd[4 * k + 3] = s.w;
        }
        #pragma unroll
        for (int k = 0; k < 64; ++k) {
            asm volatile("" : "+v"(amu[k]));
            asm volatile("" : "+v"(astd[k]));
        }
    }

    const size_t base = (size_t)b * T_ * Z_;
    float* __restrict__ zo   = out;
    float* __restrict__ muo  = out + (size_t)M_ * Z_;
    float* __restrict__ stdo = out + (size_t)2 * M_ * Z_;

    // prefetch t = 0
    float pm = pre_mu[base + j];
    float ps = pre_std[base + j];
    float ev = eps[base + j];

    float z = 0.0f;   // z_{t-1}, lane j holds element j

    for (int t = 0; t < T_; ++t) {
        // prefetch t+1 (overlaps with this step's matvec; no barrier drain)
        float pm_n = 0.f, ps_n = 0.f, ev_n = 0.f;
        if (t + 1 < T_) {
            const size_t idx = base + (size_t)(t + 1) * Z_ + j;
            pm_n = pre_mu[idx];
            ps_n = pre_std[idx];
            ev_n = eps[idx];
        }

        // wave-broadcast matvec: 4 accumulators per output to break dep chains
        const unsigned zb = __float_as_uint(z);
        float am0 = pm, am1 = 0.f, am2 = 0.f, am3 = 0.f;
        float as0 = ps, as1 = 0.f, as2 = 0.f, as3 = 0.f;
        #pragma unroll
        for (int k = 0; k < 16; ++k) {
            const float z0 = __uint_as_float(__builtin_amdgcn_readlane(zb, 4 * k + 0));
            const float z1 = __uint_as_float(__builtin_amdgcn_readlane(zb, 4 * k + 1));
            const float z2 = __uint_as_float(__builtin_amdgcn_readlane(zb, 4 * k + 2));
            const float z3 = __uint_as_float(__builtin_amdgcn_readlane(zb, 4 * k + 3));
            am0 += z0 * amu[4 * k + 0];  as0 += z0 * astd[4 * k + 0];
            am1 += z1 * amu[4 * k + 1];  as1 += z1 * astd[4 * k + 1];
            am2 += z2 * amu[4 * k + 2];  as2 += z2 * astd[4 * k + 2];
            am3 += z3 * amu[4 * k + 3];  as3 += z3 * astd[4 * k + 3];
        }
        const float mu = (am0 + am1) + (am2 + am3);
        const float sx = (as0 + as1) + (as2 + as3);
        // softplus via hw transcendentals (abs err < 1e-7 in guarded range)
        const float sp = (sx > 20.0f) ? sx : __logf(1.0f + __expf(sx));
        const float sd = sp + 1e-4f;
        z = mu + ev * sd;

        const size_t o = base + (size_t)t * Z_ + j;
        zo[o]   = z;
        muo[o]  = mu;
        stdo[o] = sd;

        pm = pm_n; ps = ps_n; ev = ev_n;
    }
}

extern "C" void kernel_launch(void* const* d_in, const int* in_sizes, int n_in,
                              void* d_out, int out_size, void* d_ws, size_t ws_size,
                              hipStream_t stream) {
    const float* input_q = (const float*)d_in[0];  // [B, T, H]
    const float* eps     = (const float*)d_in[1];  // [B, T, Z]
    const float* W_mu    = (const float*)d_in[2];  // [Z, H+Z]
    const float* b_mu    = (const float*)d_in[3];  // [Z]
    const float* W_std   = (const float*)d_in[4];  // [Z, H+Z]
    const float* b_std   = (const float*)d_in[5];  // [Z]
    float* out = (float*)d_out;

    float* pre_mu  = (float*)d_ws;                      // [M_, 64]
    float* pre_std = pre_mu + (size_t)M_ * Z_;          // [M_, 64]

    precompute_kernel<<<M_ / 64, 256, 0, stream>>>(
        input_q, W_mu, W_std, b_mu, b_std, pre_mu, pre_std);

    recurrent_kernel<<<B_, 64, 0, stream>>>(
        pre_mu, pre_std, eps, W_mu, W_std, out);
}

// Round 5
// 646.928 us; speedup vs baseline: 1.4063x; 1.0026x over previous
//
#include <hip/hip_runtime.h>
#include <math.h>

#define B_ 128
#define T_ 1024
#define H_ 256
#define Z_ 64
#define M_ (B_ * T_)   // 131072 rows

typedef float v2f __attribute__((ext_vector_type(2)));

// ---------------------------------------------------------------------------
// Kernel 1: precompute the non-recurrent part of both matmuls (unchanged).
// ---------------------------------------------------------------------------
__global__ __launch_bounds__(256) void precompute_kernel(
    const float* __restrict__ Hm,    // [M_, 256]
    const float* __restrict__ Wmu,   // [64, 320]
    const float* __restrict__ Wstd,  // [64, 320]
    const float* __restrict__ bmu,   // [64]
    const float* __restrict__ bstd,  // [64]
    float* __restrict__ pre_mu,      // [M_, 64]
    float* __restrict__ pre_std)     // [M_, 64]
{
    const int tid = threadIdx.x;
    const int ty = tid >> 4;
    const int tx = tid & 15;
    const int m0 = blockIdx.x * 64;

    __shared__ float Ash[64][17];
    __shared__ float Wm[64][17];
    __shared__ float Ws[64][17];

    float accm[4][4] = {};
    float accs[4][4] = {};

    const int lrow = tid >> 2;
    const int lk   = (tid & 3) * 4;

    for (int k0 = 0; k0 < 256; k0 += 16) {
        float4 av  = *reinterpret_cast<const float4*>(&Hm[(size_t)(m0 + lrow) * H_ + k0 + lk]);
        float4 wmv = *reinterpret_cast<const float4*>(&Wmu[(size_t)lrow * 320 + k0 + lk]);
        float4 wsv = *reinterpret_cast<const float4*>(&Wstd[(size_t)lrow * 320 + k0 + lk]);
        __syncthreads();
        Ash[lrow][lk + 0] = av.x;  Ash[lrow][lk + 1] = av.y;
        Ash[lrow][lk + 2] = av.z;  Ash[lrow][lk + 3] = av.w;
        Wm[lrow][lk + 0] = wmv.x;  Wm[lrow][lk + 1] = wmv.y;
        Wm[lrow][lk + 2] = wmv.z;  Wm[lrow][lk + 3] = wmv.w;
        Ws[lrow][lk + 0] = wsv.x;  Ws[lrow][lk + 1] = wsv.y;
        Ws[lrow][lk + 2] = wsv.z;  Ws[lrow][lk + 3] = wsv.w;
        __syncthreads();

        #pragma unroll
        for (int kk = 0; kk < 16; ++kk) {
            float a4[4], wm4[4], ws4[4];
            #pragma unroll
            for (int i = 0; i < 4; ++i) a4[i] = Ash[ty * 4 + i][kk];
            #pragma unroll
            for (int jj = 0; jj < 4; ++jj) wm4[jj] = Wm[tx * 4 + jj][kk];
            #pragma unroll
            for (int jj = 0; jj < 4; ++jj) ws4[jj] = Ws[tx * 4 + jj][kk];
            #pragma unroll
            for (int i = 0; i < 4; ++i)
                #pragma unroll
                for (int jj = 0; jj < 4; ++jj) {
                    accm[i][jj] += a4[i] * wm4[jj];
                    accs[i][jj] += a4[i] * ws4[jj];
                }
        }
    }

    float4 bm = *reinterpret_cast<const float4*>(&bmu[tx * 4]);
    float4 bs = *reinterpret_cast<const float4*>(&bstd[tx * 4]);
    #pragma unroll
    for (int i = 0; i < 4; ++i) {
        const size_t m = (size_t)(m0 + ty * 4 + i);
        float4 om, os;
        om.x = accm[i][0] + bm.x;  om.y = accm[i][1] + bm.y;
        om.z = accm[i][2] + bm.z;  om.w = accm[i][3] + bm.w;
        os.x = accs[i][0] + bs.x;  os.y = accs[i][1] + bs.y;
        os.z = accs[i][2] + bs.z;  os.w = accs[i][3] + bs.w;
        *reinterpret_cast<float4*>(&pre_mu[m * Z_ + tx * 4])  = om;
        *reinterpret_cast<float4*>(&pre_std[m * Z_ + tx * 4]) = os;
    }
}

// ---------------------------------------------------------------------------
// Kernel 2: the recurrence. One wave per batch row; lane j owns output j.
//
// R1 lesson: __syncthreads' vmcnt(0) drain killed us. But a SINGLE WAVE needs
// no barrier for LDS: ds_write -> s_waitcnt lgkmcnt(0) -> ds_read is ordered
// within a wave. So z broadcast goes back to LDS (same-address b64 reads =
// hardware broadcast, no bank conflicts), eliminating the 64 v_readlane ops
// and their SGPR-write->VALU-read hazards.
// R4 lesson: 192 scalar VALU/step was the issue floor; pack the matvec with
// v_pk_fma_f32 (full-rate packed fp32 on CDNA4) -> 64 packed FMAs.
// Weights stay as 64 v2f pairs (128 VGPRs), pinned, waves_per_eu(1,1).
// Prefetch depth 2 (HBM latency ~900cy > 1 iteration).
// ---------------------------------------------------------------------------
__global__ __launch_bounds__(64)
__attribute__((amdgpu_waves_per_eu(1, 1)))
void recurrent_kernel(
    const float* __restrict__ pre_mu,   // [M_, 64]
    const float* __restrict__ pre_std,  // [M_, 64]
    const float* __restrict__ eps,      // [B_, T_, 64]
    const float* __restrict__ Wmu,      // [64, 320]
    const float* __restrict__ Wstd,     // [64, 320]
    float* __restrict__ out)            // z | mu | std, each [B_, T_, 64]
{
    const int b = blockIdx.x;
    const int j = threadIdx.x;

    // recurrent weights as packed pairs; pinned so they can't be remat'd.
    v2f wmu2[32], wstd2[32];
    {
        const float4* wm4 = reinterpret_cast<const float4*>(&Wmu[(size_t)j * 320 + 256]);
        const float4* ws4 = reinterpret_cast<const float4*>(&Wstd[(size_t)j * 320 + 256]);
        #pragma unroll
        for (int k = 0; k < 16; ++k) {
            const float4 a = wm4[k];
            const float4 s = ws4[k];
            wmu2[2 * k + 0] = (v2f){a.x, a.y};
            wmu2[2 * k + 1] = (v2f){a.z, a.w};
            wstd2[2 * k + 0] = (v2f){s.x, s.y};
            wstd2[2 * k + 1] = (v2f){s.z, s.w};
        }
        #pragma unroll
        for (int k = 0; k < 32; ++k) {
            asm volatile("" : "+v"(wmu2[k]));
            asm volatile("" : "+v"(wstd2[k]));
        }
    }

    __shared__ __align__(16) float zs[2][64];

    const size_t base = (size_t)b * T_ * Z_;
    float* __restrict__ zo   = out;
    float* __restrict__ muo  = out + (size_t)M_ * Z_;
    float* __restrict__ stdo = out + (size_t)2 * M_ * Z_;

    // prefetch t = 0 and t = 1
    float pm0 = pre_mu[base + j];
    float ps0 = pre_std[base + j];
    float ev0 = eps[base + j];
    float pm1 = pre_mu[base + Z_ + j];
    float ps1 = pre_std[base + Z_ + j];
    float ev1 = eps[base + Z_ + j];

    float z = 0.0f;   // z_{t-1}, lane j holds element j

    for (int t = 0; t < T_; ++t) {
        // publish z_{t-1} to LDS (alternating buffer: no WAR with last iter's
        // reads), wave-internal ordering via lgkmcnt only — NO barrier.
        float* zrow = zs[t & 1];
        zrow[j] = z;
        asm volatile("s_waitcnt lgkmcnt(0)" ::: "memory");

        // prefetch t+2 (two iterations of slack > HBM latency)
        float pm2 = 0.f, ps2 = 0.f, ev2 = 0.f;
        if (t + 2 < T_) {
            const size_t idx = base + (size_t)(t + 2) * Z_ + j;
            pm2 = pre_mu[idx];
            ps2 = pre_std[idx];
            ev2 = eps[idx];
        }

        // packed matvec: z broadcast from LDS (same-address = HW broadcast),
        // 64 v_pk_fma_f32 total for both matrices.
        const v2f* __restrict__ z2 = reinterpret_cast<const v2f*>(zrow);
        v2f am01 = (v2f){pm0, 0.f}, am23 = (v2f){0.f, 0.f};
        v2f as01 = (v2f){ps0, 0.f}, as23 = (v2f){0.f, 0.f};
        #pragma unroll
        for (int k = 0; k < 16; ++k) {
            const v2f za = z2[2 * k + 0];
            const v2f zb = z2[2 * k + 1];
            asm("v_pk_fma_f32 %0, %1, %2, %0" : "+v"(am01) : "v"(za), "v"(wmu2[2 * k + 0]));
            asm("v_pk_fma_f32 %0, %1, %2, %0" : "+v"(as01) : "v"(za), "v"(wstd2[2 * k + 0]));
            asm("v_pk_fma_f32 %0, %1, %2, %0" : "+v"(am23) : "v"(zb), "v"(wmu2[2 * k + 1]));
            asm("v_pk_fma_f32 %0, %1, %2, %0" : "+v"(as23) : "v"(zb), "v"(wstd2[2 * k + 1]));
        }
        const v2f amt = am01 + am23;
        const v2f ast = as01 + as23;
        const float mu = amt.x + amt.y;
        const float sx = ast.x + ast.y;
        // softplus via hw transcendentals (abs err < 1e-7 in guarded range)
        const float sp = (sx > 20.0f) ? sx : __logf(1.0f + __expf(sx));
        const float sd = sp + 1e-4f;
        z = mu + ev0 * sd;

        const size_t o = base + (size_t)t * Z_ + j;
        zo[o]   = z;
        muo[o]  = mu;
        stdo[o] = sd;

        pm0 = pm1; ps0 = ps1; ev0 = ev1;
        pm1 = pm2; ps1 = ps2; ev1 = ev2;
    }
}

extern "C" void kernel_launch(void* const* d_in, const int* in_sizes, int n_in,
                              void* d_out, int out_size, void* d_ws, size_t ws_size,
                              hipStream_t stream) {
    const float* input_q = (const float*)d_in[0];  // [B, T, H]
    const float* eps     = (const float*)d_in[1];  // [B, T, Z]
    const float* W_mu    = (const float*)d_in[2];  // [Z, H+Z]
    const float* b_mu    = (const float*)d_in[3];  // [Z]
    const float* W_std   = (const float*)d_in[4];  // [Z, H+Z]
    const float* b_std   = (const float*)d_in[5];  // [Z]
    float* out = (float*)d_out;

    float* pre_mu  = (float*)d_ws;                      // [M_, 64]
    float* pre_std = pre_mu + (size_t)M_ * Z_;          // [M_, 64]

    precompute_kernel<<<M_ / 64, 256, 0, stream>>>(
        input_q, W_mu, W_std, b_mu, b_std, pre_mu, pre_std);

    recurrent_kernel<<<B_, 64, 0, stream>>>(
        pre_mu, pre_std, eps, W_mu, W_std, out);
}

// Round 6
// 605.360 us; speedup vs baseline: 1.5028x; 1.0687x over previous
//
#include <hip/hip_runtime.h>
#include <math.h>

#define B_ 128
#define T_ 1024
#define H_ 256
#define Z_ 64
#define M_ (B_ * T_)   // 131072 rows

typedef _Float16 h2 __attribute__((ext_vector_type(2)));
typedef _Float16 h4 __attribute__((ext_vector_type(4)));

// ---------------------------------------------------------------------------
// Kernel 1: precompute the non-recurrent part of both matmuls (unchanged).
// ---------------------------------------------------------------------------
__global__ __launch_bounds__(256) void precompute_kernel(
    const float* __restrict__ Hm,    // [M_, 256]
    const float* __restrict__ Wmu,   // [64, 320]
    const float* __restrict__ Wstd,  // [64, 320]
    const float* __restrict__ bmu,   // [64]
    const float* __restrict__ bstd,  // [64]
    float* __restrict__ pre_mu,      // [M_, 64]
    float* __restrict__ pre_std)     // [M_, 64]
{
    const int tid = threadIdx.x;
    const int ty = tid >> 4;
    const int tx = tid & 15;
    const int m0 = blockIdx.x * 64;

    __shared__ float Ash[64][17];
    __shared__ float Wm[64][17];
    __shared__ float Ws[64][17];

    float accm[4][4] = {};
    float accs[4][4] = {};

    const int lrow = tid >> 2;
    const int lk   = (tid & 3) * 4;

    for (int k0 = 0; k0 < 256; k0 += 16) {
        float4 av  = *reinterpret_cast<const float4*>(&Hm[(size_t)(m0 + lrow) * H_ + k0 + lk]);
        float4 wmv = *reinterpret_cast<const float4*>(&Wmu[(size_t)lrow * 320 + k0 + lk]);
        float4 wsv = *reinterpret_cast<const float4*>(&Wstd[(size_t)lrow * 320 + k0 + lk]);
        __syncthreads();
        Ash[lrow][lk + 0] = av.x;  Ash[lrow][lk + 1] = av.y;
        Ash[lrow][lk + 2] = av.z;  Ash[lrow][lk + 3] = av.w;
        Wm[lrow][lk + 0] = wmv.x;  Wm[lrow][lk + 1] = wmv.y;
        Wm[lrow][lk + 2] = wmv.z;  Wm[lrow][lk + 3] = wmv.w;
        Ws[lrow][lk + 0] = wsv.x;  Ws[lrow][lk + 1] = wsv.y;
        Ws[lrow][lk + 2] = wsv.z;  Ws[lrow][lk + 3] = wsv.w;
        __syncthreads();

        #pragma unroll
        for (int kk = 0; kk < 16; ++kk) {
            float a4[4], wm4[4], ws4[4];
            #pragma unroll
            for (int i = 0; i < 4; ++i) a4[i] = Ash[ty * 4 + i][kk];
            #pragma unroll
            for (int jj = 0; jj < 4; ++jj) wm4[jj] = Wm[tx * 4 + jj][kk];
            #pragma unroll
            for (int jj = 0; jj < 4; ++jj) ws4[jj] = Ws[tx * 4 + jj][kk];
            #pragma unroll
            for (int i = 0; i < 4; ++i)
                #pragma unroll
                for (int jj = 0; jj < 4; ++jj) {
                    accm[i][jj] += a4[i] * wm4[jj];
                    accs[i][jj] += a4[i] * ws4[jj];
                }
        }
    }

    float4 bm = *reinterpret_cast<const float4*>(&bmu[tx * 4]);
    float4 bs = *reinterpret_cast<const float4*>(&bstd[tx * 4]);
    #pragma unroll
    for (int i = 0; i < 4; ++i) {
        const size_t m = (size_t)(m0 + ty * 4 + i);
        float4 om, os;
        om.x = accm[i][0] + bm.x;  om.y = accm[i][1] + bm.y;
        om.z = accm[i][2] + bm.z;  om.w = accm[i][3] + bm.w;
        os.x = accs[i][0] + bs.x;  os.y = accs[i][1] + bs.y;
        os.z = accs[i][2] + bs.z;  os.w = accs[i][3] + bs.w;
        *reinterpret_cast<float4*>(&pre_mu[m * Z_ + tx * 4])  = om;
        *reinterpret_cast<float4*>(&pre_std[m * Z_ + tx * 4]) = os;
    }
}

// ---------------------------------------------------------------------------
// Kernel 2: the recurrence. One wave per batch row; lane j owns output j.
//
// R5 lesson: the allocator will NOT hold 128 f32 weight VGPRs (spills ~900
// cy/step of memory stall onto the serial path; VALUBusy 4.9% proves the
// stall is memory, not issue). Fix: halve the footprint. Weights as packed
// f16 pairs (64 VGPRs total for both matrices), matvec via v_dot2_f32_f16
// (full-rate f16 dot2, f32 accumulate). z broadcast through LDS as f16:
// ds_write_b16 + same-address ds_read_b64 -> ready-packed half2 operands.
// Single wave => no barrier; lgkmcnt(0) orders write->read (R1 lesson).
// Precision: |w|<0.3, f16 rel err 5e-4, recurrence is a contraction
// (||Wz||~0.9) -> steady-state absmax ~0.05 << 0.31 threshold.
// ---------------------------------------------------------------------------
__global__ __launch_bounds__(64)
__attribute__((amdgpu_waves_per_eu(1, 1)))
void recurrent_kernel(
    const float* __restrict__ pre_mu,   // [M_, 64]
    const float* __restrict__ pre_std,  // [M_, 64]
    const float* __restrict__ eps,      // [B_, T_, 64]
    const float* __restrict__ Wmu,      // [64, 320]
    const float* __restrict__ Wstd,     // [64, 320]
    float* __restrict__ out)            // z | mu | std, each [B_, T_, 64]
{
    const int b = blockIdx.x;
    const int j = threadIdx.x;

    // recurrent weights as packed f16 pairs: 32+32 regs = 64 VGPRs total.
    h2 wmuh[32], wstdh[32];
    {
        const float4* wm4 = reinterpret_cast<const float4*>(&Wmu[(size_t)j * 320 + 256]);
        const float4* ws4 = reinterpret_cast<const float4*>(&Wstd[(size_t)j * 320 + 256]);
        #pragma unroll
        for (int k = 0; k < 16; ++k) {
            const float4 a = wm4[k];
            const float4 s = ws4[k];
            wmuh[2 * k + 0] = (h2){(_Float16)a.x, (_Float16)a.y};
            wmuh[2 * k + 1] = (h2){(_Float16)a.z, (_Float16)a.w};
            wstdh[2 * k + 0] = (h2){(_Float16)s.x, (_Float16)s.y};
            wstdh[2 * k + 1] = (h2){(_Float16)s.z, (_Float16)s.w};
        }
        #pragma unroll
        for (int k = 0; k < 32; ++k) {
            asm volatile("" : "+v"(wmuh[k]));
            asm volatile("" : "+v"(wstdh[k]));
        }
    }

    __shared__ __align__(16) _Float16 zs[2][64];

    const size_t base = (size_t)b * T_ * Z_;
    float* __restrict__ zo   = out;
    float* __restrict__ muo  = out + (size_t)M_ * Z_;
    float* __restrict__ stdo = out + (size_t)2 * M_ * Z_;

    // prefetch t = 0 and t = 1
    float pm0 = pre_mu[base + j];
    float ps0 = pre_std[base + j];
    float ev0 = eps[base + j];
    float pm1 = pre_mu[base + Z_ + j];
    float ps1 = pre_std[base + Z_ + j];
    float ev1 = eps[base + Z_ + j];

    float z = 0.0f;   // z_{t-1}, lane j holds element j

    for (int t = 0; t < T_; ++t) {
        // publish z_{t-1} as f16 (alternating buffer), wave-internal ordering
        // via lgkmcnt only — NO barrier.
        _Float16* zrow = zs[t & 1];
        zrow[j] = (_Float16)z;
        asm volatile("s_waitcnt lgkmcnt(0)" ::: "memory");

        // prefetch t+2 (two iterations of slack > HBM latency)
        float pm2 = 0.f, ps2 = 0.f, ev2 = 0.f;
        if (t + 2 < T_) {
            const size_t idx = base + (size_t)(t + 2) * Z_ + j;
            pm2 = pre_mu[idx];
            ps2 = pre_std[idx];
            ev2 = eps[idx];
        }

        // f16 matvec: 16 broadcast b64 reads give 4 halves each; dot2 pairs
        // come free as register halves. 64 fdot2 total; 4 rotating
        // accumulators -> 8-deep chains.
        const h4* __restrict__ z4 = reinterpret_cast<const h4*>(zrow);
        float am[4] = {pm0, 0.f, 0.f, 0.f};
        float as[4] = {ps0, 0.f, 0.f, 0.f};
        #pragma unroll
        for (int k = 0; k < 16; ++k) {
            const h4 q = z4[k];
            const h2 lo = __builtin_shufflevector(q, q, 0, 1);
            const h2 hi = __builtin_shufflevector(q, q, 2, 3);
            const int a = k & 3;
            am[a] = __builtin_amdgcn_fdot2(lo, wmuh[2 * k + 0], am[a], false);
            as[a] = __builtin_amdgcn_fdot2(lo, wstdh[2 * k + 0], as[a], false);
            am[a] = __builtin_amdgcn_fdot2(hi, wmuh[2 * k + 1], am[a], false);
            as[a] = __builtin_amdgcn_fdot2(hi, wstdh[2 * k + 1], as[a], false);
        }
        const float mu = (am[0] + am[1]) + (am[2] + am[3]);
        const float sx = (as[0] + as[1]) + (as[2] + as[3]);
        // softplus via hw transcendentals (abs err < 1e-7 in guarded range)
        const float sp = (sx > 20.0f) ? sx : __logf(1.0f + __expf(sx));
        const float sd = sp + 1e-4f;
        z = mu + ev0 * sd;

        const size_t o = base + (size_t)t * Z_ + j;
        zo[o]   = z;
        muo[o]  = mu;
        stdo[o] = sd;

        pm0 = pm1; ps0 = ps1; ev0 = ev1;
        pm1 = pm2; ps1 = ps2; ev1 = ev2;
    }
}

extern "C" void kernel_launch(void* const* d_in, const int* in_sizes, int n_in,
                              void* d_out, int out_size, void* d_ws, size_t ws_size,
                              hipStream_t stream) {
    const float* input_q = (const float*)d_in[0];  // [B, T, H]
    const float* eps     = (const float*)d_in[1];  // [B, T, Z]
    const float* W_mu    = (const float*)d_in[2];  // [Z, H+Z]
    const float* b_mu    = (const float*)d_in[3];  // [Z]
    const float* W_std   = (const float*)d_in[4];  // [Z, H+Z]
    const float* b_std   = (const float*)d_in[5];  // [Z]
    float* out = (float*)d_out;

    float* pre_mu  = (float*)d_ws;                      // [M_, 64]
    float* pre_std = pre_mu + (size_t)M_ * Z_;          // [M_, 64]

    precompute_kernel<<<M_ / 64, 256, 0, stream>>>(
        input_q, W_mu, W_std, b_mu, b_std, pre_mu, pre_std);

    recurrent_kernel<<<B_, 64, 0, stream>>>(
        pre_mu, pre_std, eps, W_mu, W_std, out);
}